// Round 16
// baseline (4678.041 us; speedup 1.0000x reference)
//
#include <hip/hip_runtime.h>
#include <cstdint>
#include <cstddef>
#include <math.h>

#define A_N   1024
#define OBS_N 2048
#define TD_N  256
#define H_N   128
#define M_N   16
#define AE_N  64
#define NWGC  32   // k_scan grid: 32 WGs (16 step-pairs), 1 WG/CU (LDS-forced)

typedef _Float16 h2 __attribute__((ext_vector_type(2)));
typedef _Float16 f16x8 __attribute__((ext_vector_type(8)));
typedef float f32x4 __attribute__((ext_vector_type(4)));

__device__ __forceinline__ float sigf(float x) { return 1.0f / (1.0f + expf(-x)); }
__device__ __forceinline__ h2 u2h(unsigned int u) { union { unsigned int x; h2 h; } c; c.x = u; return c.h; }
__device__ __forceinline__ unsigned int packh(float a, float b) {
  union { h2 h; unsigned int u; } c;
  c.h = (h2){(_Float16)a, (_Float16)b};
  return c.u;
}

// C may arrive as uint8 (1B/elem) or int32 (4B/elem). Detect on device.
__device__ __forceinline__ bool c_at(const unsigned char* C, int as_int, size_t idx) {
  return as_int ? (((const int*)C)[idx] != 0) : (C[idx] != 0);
}

__global__ __launch_bounds__(64) void k_cdet(const unsigned char* __restrict__ C, int* __restrict__ flag) {
  int lane = threadIdx.x;
  int cnt = 0;
  for (int i = lane; i < 4096; i += 64) cnt += (C[i] != 0) ? 1 : 0;
  for (int off = 32; off; off >>= 1) cnt += __shfl_down(cnt, off);
  if (lane == 0) flag[0] = (cnt < 40) ? 1 : 0;
}

// ---------------- k1: t = relu(LN(obs@W1 + b1)) ----------------
__global__ __launch_bounds__(256) void k_actor1a(const float* __restrict__ obs,
    const float* __restrict__ W1, const float* __restrict__ b1,
    const float* __restrict__ g1, const float* __restrict__ bt1,
    float* __restrict__ tout) {
  __shared__ float S[4 * OBS_N];
  __shared__ float red[4][4][2];
  int tid = threadIdx.x;
  int r0 = blockIdx.x * 4;
  {
    const float4* src = (const float4*)(obs + (size_t)r0 * OBS_N);
    float4* dst = (float4*)S;
    for (int i = tid; i < 4 * OBS_N / 4; i += 256) dst[i] = src[i];
  }
  __syncthreads();
  int j = tid;
  float acc0 = 0, acc1 = 0, acc2 = 0, acc3 = 0;
  const float4* S4 = (const float4*)S;
  for (int k4 = 0; k4 < OBS_N / 4; k4++) {
    float w0 = W1[(k4 * 4 + 0) * TD_N + j];
    float w1 = W1[(k4 * 4 + 1) * TD_N + j];
    float w2 = W1[(k4 * 4 + 2) * TD_N + j];
    float w3 = W1[(k4 * 4 + 3) * TD_N + j];
    float4 s0 = S4[0 * 512 + k4], s1 = S4[1 * 512 + k4], s2 = S4[2 * 512 + k4], s3 = S4[3 * 512 + k4];
    acc0 += s0.x * w0 + s0.y * w1 + s0.z * w2 + s0.w * w3;
    acc1 += s1.x * w0 + s1.y * w1 + s1.z * w2 + s1.w * w3;
    acc2 += s2.x * w0 + s2.y * w1 + s2.z * w2 + s2.w * w3;
    acc3 += s3.x * w0 + s3.y * w1 + s3.z * w2 + s3.w * w3;
  }
  float z[4] = {acc0 + b1[j], acc1 + b1[j], acc2 + b1[j], acc3 + b1[j]};
  int w = tid >> 6, lane = tid & 63;
  for (int r = 0; r < 4; r++) {
    float v = z[r], v2 = z[r] * z[r];
    for (int off = 32; off; off >>= 1) { v += __shfl_down(v, off); v2 += __shfl_down(v2, off); }
    if (lane == 0) { red[r][w][0] = v; red[r][w][1] = v2; }
  }
  __syncthreads();
  for (int r = 0; r < 4; r++) {
    float sm = red[r][0][0] + red[r][1][0] + red[r][2][0] + red[r][3][0];
    float sq = red[r][0][1] + red[r][1][1] + red[r][2][1] + red[r][3][1];
    float mean = sm * (1.0f / TD_N);
    float var = sq * (1.0f / TD_N) - mean * mean;
    float rs = 1.0f / sqrtf(var + 1e-5f);
    float val = (z[r] - mean) * rs * g1[j] + bt1[j];
    tout[(size_t)(r0 + r) * TD_N + j] = fmaxf(val, 0.0f);
  }
}

// ---------------- k2: thoughts = LN(t@W2 + b2) -> thA (= d_out) ----------------
__global__ __launch_bounds__(256) void k_actor1b(const float* __restrict__ tin,
    const float* __restrict__ W2, const float* __restrict__ b2,
    const float* __restrict__ g2, const float* __restrict__ bt2,
    float* __restrict__ th) {
  __shared__ float S[4 * TD_N];
  __shared__ float red[4][4][2];
  int tid = threadIdx.x;
  int r0 = blockIdx.x * 4;
  for (int i = tid; i < 4 * TD_N; i += 256) S[i] = tin[(size_t)r0 * TD_N + i];
  __syncthreads();
  int j = tid;
  float z[4] = {0, 0, 0, 0};
  const float4* S4 = (const float4*)S;
  for (int k4 = 0; k4 < TD_N / 4; k4++) {
    float w0 = W2[(k4 * 4 + 0) * TD_N + j];
    float w1 = W2[(k4 * 4 + 1) * TD_N + j];
    float w2v = W2[(k4 * 4 + 2) * TD_N + j];
    float w3 = W2[(k4 * 4 + 3) * TD_N + j];
#pragma unroll
    for (int r = 0; r < 4; r++) {
      float4 sv = S4[r * 64 + k4];
      z[r] += sv.x * w0 + sv.y * w1 + sv.z * w2v + sv.w * w3;
    }
  }
  for (int r = 0; r < 4; r++) z[r] += b2[j];
  int w = tid >> 6, lane = tid & 63;
  for (int r = 0; r < 4; r++) {
    float v = z[r], v2 = z[r] * z[r];
    for (int off = 32; off; off >>= 1) { v += __shfl_down(v, off); v2 += __shfl_down(v2, off); }
    if (lane == 0) { red[r][w][0] = v; red[r][w][1] = v2; }
  }
  __syncthreads();
  for (int r = 0; r < 4; r++) {
    float sm = red[r][0][0] + red[r][1][0] + red[r][2][0] + red[r][3][0];
    float sq = red[r][0][1] + red[r][1][1] + red[r][2][1] + red[r][3][1];
    float mean = sm * (1.0f / TD_N);
    float var = sq * (1.0f / TD_N) - mean * mean;
    float rs = 1.0f / sqrtf(var + 1e-5f);
    th[(size_t)(r0 + r) * TD_N + j] = (z[r] - mean) * rs * g2[j] + bt2[j];
  }
}

// ---------------- k3: attention unit -> is_init (fp64: x>0 decision is razor-thin) ----------------
__global__ __launch_bounds__(256) void k_att(const float* __restrict__ th,
    const float* __restrict__ aW1, const float* __restrict__ ab1,
    const float* __restrict__ aW2, const float* __restrict__ ab2,
    const float* __restrict__ aW3, const float* __restrict__ ab3,
    int* __restrict__ isin) {
  __shared__ float S[4 * TD_N];
  __shared__ double A1[4 * AE_N];
  __shared__ double A2[4 * AE_N];
  int tid = threadIdx.x;
  int r0 = blockIdx.x * 4;
  for (int i = tid; i < 4 * TD_N; i += 256) S[i] = th[(size_t)r0 * TD_N + i];
  __syncthreads();
  int r = tid >> 6, c = tid & 63;
  double acc = 0;
  for (int k = 0; k < TD_N; k++) acc += (double)S[r * TD_N + k] * (double)aW1[k * AE_N + c];
  acc += (double)ab1[c];
  A1[r * AE_N + c] = acc > 0.0 ? acc : 0.0;
  __syncthreads();
  acc = 0;
  for (int k = 0; k < AE_N; k++) acc += A1[r * AE_N + k] * (double)aW2[k * AE_N + c];
  acc += (double)ab2[c];
  A2[r * AE_N + c] = acc > 0.0 ? acc : 0.0;
  __syncthreads();
  double p = A2[r * AE_N + c] * (double)aW3[c];
  for (int off = 32; off; off >>= 1) p += __shfl_down(p, off);
  if (c == 0) isin[r0 + r] = ((p + (double)ab3[0]) > 0.0) ? 1 : 0;
}

// ---------------- k_memb: member indices (ascending) per row ----------------
__global__ __launch_bounds__(64) void k_memb(const unsigned char* __restrict__ C,
    const int* __restrict__ flag, int* __restrict__ memb) {
  int s = blockIdx.x, lane = threadIdx.x;
  int as_int = flag[0];
  if (lane < M_N) memb[s * M_N + lane] = lane;  // safe defaults (never poison)
  __syncthreads();
  int base = 0;
  for (int ch = 0; ch < 16; ch++) {
    int col = ch * 64 + lane;
    bool v = c_at(C, as_int, (size_t)s * A_N + col);
    unsigned long long m = __ballot(v);
    if (v) {
      int pos = base + __popcll(m & ((1ull << lane) - 1ull));
      if (pos < M_N) memb[s * M_N + pos] = col;
    }
    base += __popcll(m);
  }
}

// ---------------- k_req: write ordinal per (step, member slot) ----------------
__global__ __launch_bounds__(256) void k_req(const unsigned char* __restrict__ C,
    const int* __restrict__ flag, const int* __restrict__ memb,
    const int* __restrict__ isin, int* __restrict__ req) {
  __shared__ int Ls[A_N];
  int s = blockIdx.x, tid = threadIdx.x;
  int as_int = flag[0];
  for (int i = tid; i < A_N; i += 256) Ls[i] = isin[i];
  __syncthreads();
  int i = tid >> 4, sub = tid & 15;
  int m = memb[s * M_N + i] & (A_N - 1);
  int cnt = 0;
  for (int s2 = sub; s2 < s; s2 += 16)
    if (Ls[s2] && c_at(C, as_int, (size_t)s2 * A_N + m)) cnt++;
  for (int off = 1; off < 16; off <<= 1) cnt += __shfl_xor(cnt, off);
  if (sub == 0) req[s * M_N + i] = cnt;
}

// ---------------- k_prep: weight re-layouts, bias sums, version-counter reset ----------------
// wfrag: MFMA B-fragment order (natural gate index).
// whhp: packed fp16 pairs in k_scan's REMAPPED thread order:
//   thread t owns gate gmap(t) = (t&3)*128 + (t>>2)  (4 gates of unit t>>2 in 4 lanes)
__global__ __launch_bounds__(256) void k_prep(
    const float* __restrict__ Wih_f, const float* __restrict__ Wih_r,
    const float* __restrict__ Whh_f, const float* __restrict__ Whh_r,
    const float* __restrict__ bih_f, const float* __restrict__ bhh_f,
    const float* __restrict__ bih_r, const float* __restrict__ bhh_r,
    unsigned int* __restrict__ wfragf, unsigned int* __restrict__ wfragr,
    unsigned int* __restrict__ whhpf, unsigned int* __restrict__ whhpr,
    float* __restrict__ bsumf, float* __restrict__ bsumr,
    int* __restrict__ verF, int* __restrict__ verB) {
  int id = blockIdx.x * 256 + threadIdx.x;  // 512*256 = 131072
  if (id < 65536) {
    int j = id & 3, l = (id >> 2) & 63, tile = (id >> 8) & 31, c = id >> 13;
    int gate = tile * 16 + (l & 15);
    int k = c * 32 + ((l >> 4) << 3) + (j << 1);
    wfragf[id] = packh(Wih_f[gate * TD_N + k], Wih_f[gate * TD_N + k + 1]);
    wfragr[id] = packh(Wih_r[gate * TD_N + k], Wih_r[gate * TD_N + k + 1]);
  }
  if (id < 32768) {
    int t = id & 511, k2 = id >> 9;
    int g = (t & 3) * 128 + (t >> 2);   // remapped gate ownership
    whhpf[id] = packh(Whh_f[g * H_N + 2 * k2], Whh_f[g * H_N + 2 * k2 + 1]);
    whhpr[id] = packh(Whh_r[g * H_N + 2 * k2], Whh_r[g * H_N + 2 * k2 + 1]);
  }
  if (id < 512) { bsumf[id] = bih_f[id] + bhh_f[id]; bsumr[id] = bih_r[id] + bhh_r[id]; }
  if (id < A_N) { verF[id] = 0; verB[id] = 0; }
}

// ---------------- k_lvl: level-sorted active-step list (single wave, LDS-resident) ----------------
__global__ __launch_bounds__(64) void k_lvl(const int* __restrict__ isin,
    const int* __restrict__ memb, int* __restrict__ fin,
    int* __restrict__ lstart, int* __restrict__ llist) {
  __shared__ int membS[A_N * M_N];        // 64 KB
  __shared__ int last[A_N];               // 4 KB
  __shared__ int cnt[A_N + 2];            // 4 KB
  __shared__ int cur[A_N + 2];            // 4 KB
  __shared__ short lvlS[A_N];             // 2 KB
  __shared__ unsigned char isinS[A_N];    // 1 KB
  __shared__ unsigned char cntm[A_N];     // 1 KB
  int lane = threadIdx.x;
  for (int i = lane; i < A_N * M_N; i += 64) membS[i] = memb[i] & (A_N - 1);
  for (int i = lane; i < A_N; i += 64) {
    isinS[i] = (unsigned char)(isin[i] != 0);
    last[i] = 0; cntm[i] = 0; lvlS[i] = 0;
  }
  for (int l = lane; l < A_N + 2; l += 64) cnt[l] = 0;
  __syncthreads();
  for (int s = 0; s < A_N; s++) {
    if (isinS[s]) {             // uniform branch (LDS broadcast)
      int li = 0, m = 0;
      if (lane < 16) { m = membS[s * M_N + lane]; li = last[m]; }
#pragma unroll
      for (int off = 8; off; off >>= 1) li = max(li, __shfl_xor(li, off));
      int L = __shfl(li, 0) + 1;
      if (lane < 16) { last[m] = L; cntm[m]++; }
      if (lane == 0) { lvlS[s] = (short)L; cnt[L]++; }
    }
  }
  if (lane == 0) {
    int acc = 0;
    for (int L = 1; L <= A_N; L++) { cur[L] = acc; acc += cnt[L]; }
    lstart[0] = acc;  // nact
    for (int s = 0; s < A_N; s++) {
      int L = lvlS[s];
      if (L > 0) llist[cur[L]++] = s;
    }
  }
  for (int i = lane; i < A_N; i += 64) fin[i] = cntm[i] & 1;
}

// ---------------- k_scan: dataflow scan, MFMA transform, 1-barrier recurrence ----------------
// R15 with the divergent-shfl BUG FIXED: the h-pack shuffle now executes in
// ALL lanes (source lane always active), leaders just use the result. R15's
// `__shfl` inside `if((tid&7)==0)` read from EXEC-masked lanes -> undefined
// on CDNA -> corrupted h history (absmax 0.41).
// Thread tid owns gate gmap(tid) = (tid&3)*128 + (tid>>2): the 4 gates of
// hidden unit (tid>>2) sit in 4 consecutive lanes of one wave, so the c/h
// update is 4 intra-wave shfls (free) and only the hp ping-pong RAW barrier
// remains (1 per timestep, was 2).
#define RSH 264   // Sh row stride in halves (528 B = 33*16)
__global__ __launch_bounds__(512)
void k_scan(
    float* __restrict__ thA, float* __restrict__ thB,
    const int* __restrict__ lstart, const int* __restrict__ llist,
    const int* __restrict__ memb, const int* __restrict__ req,
    int* __restrict__ verF, int* __restrict__ verB,
    const unsigned int* __restrict__ wfragf, const unsigned int* __restrict__ wfragr,
    const unsigned int* __restrict__ whhpf, const unsigned int* __restrict__ whhpr,
    const float* __restrict__ bsumf, const float* __restrict__ bsumr) {
  __shared__ __align__(16) unsigned short Sh[16 * RSH];  // 8448 B (fp16 S)
  __shared__ float xa_lds[16 * 512 + 10240];             // 32 KB used + 40 KB pad (1 WG/CU)
  __shared__ unsigned int hp[2 * 64];                    // packed fp16 h ping-pong
  __shared__ int memb_s[16];
  __shared__ int par_s[16];
  int tid = threadIdx.x;
  int wg = blockIdx.x;
  int dir = wg & 1;
  int pair = wg >> 1;
  int dmask = dir ? 15 : 0;
  const unsigned int* wfrag = dir ? wfragr : wfragf;
  const unsigned int* whhp = dir ? whhpr : whhpf;
  int gmap = (tid & 3) * 128 + (tid >> 2);   // owned gate (remapped)
  int unit = tid >> 2;                        // owned hidden unit
  float blo = (dir ? bsumr : bsumf)[gmap];
  int gtype = tid & 3;                        // 0=i 1=f 2=g 3=o
  int* vown = dir ? verB : verF;
  int wv = tid >> 6, lane = tid & 63;
  int lane4 = lane & ~3;
  int fm = lane & 15, fkg = lane >> 4;
  // Whh column (remapped gate) in registers, packed fp16: 64 VGPRs, asm-pinned
  unsigned int wreg[64];
#pragma unroll
  for (int k2 = 0; k2 < 64; k2++) wreg[k2] = whhp[k2 * 512 + tid];
#pragma unroll
  for (int k2 = 0; k2 < 64; k2++) asm volatile("" : "+v"(wreg[k2]));

  int nact = lstart[0];
  for (int idx = pair; idx < nact; idx += NWGC / 2) {
    int s = llist[idx];
    if (tid < 16) {
      int m = memb[s * M_N + tid] & (A_N - 1);
      int rq = req[s * M_N + tid];
      memb_s[tid] = m;
      par_s[tid] = rq & 1;
      int tries = 0;
      while (__hip_atomic_load(&verF[m], __ATOMIC_RELAXED, __HIP_MEMORY_SCOPE_AGENT) < rq ||
             __hip_atomic_load(&verB[m], __ATOMIC_RELAXED, __HIP_MEMORY_SCOPE_AGENT) < rq) {
        __builtin_amdgcn_s_sleep(1);
        if (++tries > (1 << 21)) break;  // failsafe: wrong-answer beats hang
      }
    }
    __syncthreads();
    {  // gather 16 member rows -> packed fp16 Sh (dir=1 stores reversed order)
      int r = tid >> 5, p = tid & 31;
      int j = r ^ dmask;
      const float* src = (par_s[j] ? thB : thA) + (size_t)memb_s[j] * TD_N + p * 8;
      float v[8];
#pragma unroll
      for (int q = 0; q < 8; q++)
        v[q] = __hip_atomic_load(src + q, __ATOMIC_RELAXED, __HIP_MEMORY_SCOPE_AGENT);
      uint4 pk;
      pk.x = packh(v[0], v[1]); pk.y = packh(v[2], v[3]);
      pk.z = packh(v[4], v[5]); pk.w = packh(v[6], v[7]);
      *(uint4*)((char*)Sh + r * 528 + p * 16) = pk;
    }
    __syncthreads();
    // ---- MFMA transform: xa[t][g] = S . Wih  (bias added later)
    {
#pragma unroll
      for (int t4 = 0; t4 < 4; t4++) {
        int tile = wv * 4 + t4;
        f32x4 acc = {0.0f, 0.0f, 0.0f, 0.0f};
#pragma unroll 2
        for (int c = 0; c < 8; c++) {
          f16x8 af = *(const f16x8*)((const char*)Sh + fm * 528 + c * 64 + fkg * 16);
          union { uint4 u; f16x8 h; } bu;
          bu.u = *(const uint4*)(wfrag + ((size_t)(c * 32 + tile) * 64 + lane) * 4);
          acc = __builtin_amdgcn_mfma_f32_16x16x32_f16(af, bu.h, acc, 0, 0, 0);
        }
#pragma unroll
        for (int r = 0; r < 4; r++)
          xa_lds[(fkg * 4 + r) * 512 + tile * 16 + fm] = acc[r];
      }
    }
    if (tid < 64) hp[tid] = 0u;  // h0 = 0 (packed), buf 0
    float cst = 0.0f;
    __syncthreads();
    // ---- recurrence: ONE barrier per timestep; gate exchange via intra-wave shfl
#pragma unroll
    for (int u = 0; u < 16; u++) {
      float xau = xa_lds[u * 512 + gmap] + blo;
      const uint4* hp4 = (const uint4*)(hp + (u & 1) * 64);
      float z0 = 0, z1 = 0, z2 = 0, z3 = 0, z4 = 0, z5 = 0, z6 = 0, z7 = 0;
#pragma unroll
      for (int j = 0; j < 16; j += 2) {
        uint4 ha = hp4[j], hb = hp4[j + 1];  // broadcast reads
        z0 = __builtin_amdgcn_fdot2(u2h(wreg[4 * j + 0]), u2h(ha.x), z0, false);
        z1 = __builtin_amdgcn_fdot2(u2h(wreg[4 * j + 1]), u2h(ha.y), z1, false);
        z2 = __builtin_amdgcn_fdot2(u2h(wreg[4 * j + 2]), u2h(ha.z), z2, false);
        z3 = __builtin_amdgcn_fdot2(u2h(wreg[4 * j + 3]), u2h(ha.w), z3, false);
        z4 = __builtin_amdgcn_fdot2(u2h(wreg[4 * j + 4]), u2h(hb.x), z4, false);
        z5 = __builtin_amdgcn_fdot2(u2h(wreg[4 * j + 5]), u2h(hb.y), z5, false);
        z6 = __builtin_amdgcn_fdot2(u2h(wreg[4 * j + 6]), u2h(hb.z), z6, false);
        z7 = __builtin_amdgcn_fdot2(u2h(wreg[4 * j + 7]), u2h(hb.w), z7, false);
      }
      float z = xau + ((z0 + z1) + (z2 + z3)) + ((z4 + z5) + (z6 + z7));
      float gate = (gtype == 2) ? tanhf(z) : sigf(z);
      // 4 gates of this unit live in lanes lane4..lane4+3 of this wave
      float gi = __shfl(gate, lane4 + 0);
      float gf = __shfl(gate, lane4 + 1);
      float gg = __shfl(gate, lane4 + 2);
      float go = __shfl(gate, lane4 + 3);
      cst = gf * cst + gi * gg;               // redundant in all 4 lanes (consistent)
      float hv = go * tanhf(cst);
      // non-divergent pack shuffle: ALL lanes execute (source lane always active);
      // leader (lane&7==0) pairs its unit 2t with lane|4's unit 2t+1
      float hvn = __shfl(hv, lane | 4);
      int r2 = u ^ dmask;                     // fwd: u; bwd: 15-u (rev-aligned)
      if ((tid & 7) == 0)
        hp[((u + 1) & 1) * 64 + (tid >> 3)] = packh(hv, hvn);
      if ((tid & 3) == 0) {                   // one lane per unit stores to global
        float* dst = par_s[r2] ? thA : thB;
        __hip_atomic_store(dst + (size_t)memb_s[r2] * TD_N + dir * H_N + unit, hv,
                           __ATOMIC_RELAXED, __HIP_MEMORY_SCOPE_AGENT);
      }
      __syncthreads();  // hp RAW barrier; also drains vmcnt (row r2 stores done)
      // EARLY publish: row r2 is final for this dir -> release it now
      if (tid == 0)
        __hip_atomic_fetch_add(&vown[memb_s[r2]], 1, __ATOMIC_RELAXED, __HIP_MEMORY_SCOPE_AGENT);
    }
  }
}

// ---------------- k_actor2: acts = tanh(LN(LN(relu(th)@W3+b3)@W4+b4)) ----------------
__global__ __launch_bounds__(256) void k_actor2(const float* __restrict__ thA, const float* __restrict__ thB,
    const int* __restrict__ fin,
    const float* __restrict__ W3, const float* __restrict__ b3,
    const float* __restrict__ g3, const float* __restrict__ bt3,
    const float* __restrict__ W4, const float* __restrict__ b4,
    const float* __restrict__ g4, const float* __restrict__ bt4,
    float* __restrict__ out) {
  __shared__ float Hs[4 * TD_N];
  __shared__ float H3[4 * TD_N];
  __shared__ float red[4][4][2];
  int tid = threadIdx.x;
  int r0 = blockIdx.x * 4;
  int j = tid;
  for (int i = tid; i < 4 * TD_N; i += 256) {
    int r = i >> 8, col = i & 255;
    int row = r0 + r;
    const float* src = (fin[row] ? thB : thA) + (size_t)row * TD_N + col;
    float v = __hip_atomic_load(src, __ATOMIC_RELAXED, __HIP_MEMORY_SCOPE_AGENT);
    Hs[i] = fmaxf(v, 0.0f);
  }
  __syncthreads();  // all reads of own rows complete before any write below
  float z[4] = {0, 0, 0, 0};
  {
    const float4* S4 = (const float4*)Hs;
    for (int k4 = 0; k4 < 64; k4++) {
      float w0 = W3[(k4 * 4 + 0) * TD_N + j];
      float w1 = W3[(k4 * 4 + 1) * TD_N + j];
      float w2 = W3[(k4 * 4 + 2) * TD_N + j];
      float w3v = W3[(k4 * 4 + 3) * TD_N + j];
#pragma unroll
      for (int r = 0; r < 4; r++) {
        float4 sv = S4[r * 64 + k4];
        z[r] += sv.x * w0 + sv.y * w1 + sv.z * w2 + sv.w * w3v;
      }
    }
  }
  for (int r = 0; r < 4; r++) z[r] += b3[j];
  int w = tid >> 6, lane = tid & 63;
  for (int r = 0; r < 4; r++) {
    float v = z[r], v2 = z[r] * z[r];
    for (int off = 32; off; off >>= 1) { v += __shfl_down(v, off); v2 += __shfl_down(v2, off); }
    if (lane == 0) { red[r][w][0] = v; red[r][w][1] = v2; }
  }
  __syncthreads();
  for (int r = 0; r < 4; r++) {
    float sm = red[r][0][0] + red[r][1][0] + red[r][2][0] + red[r][3][0];
    float sq = red[r][0][1] + red[r][1][1] + red[r][2][1] + red[r][3][1];
    float mean = sm * (1.0f / TD_N);
    float var = sq * (1.0f / TD_N) - mean * mean;
    float rs = 1.0f / sqrtf(var + 1e-5f);
    H3[r * TD_N + j] = (z[r] - mean) * rs * g3[j] + bt3[j];
  }
  __syncthreads();
  float z2a[4] = {0, 0, 0, 0};
  {
    const float4* S4 = (const float4*)H3;
    for (int k4 = 0; k4 < 64; k4++) {
      float w0 = W4[(k4 * 4 + 0) * TD_N + j];
      float w1 = W4[(k4 * 4 + 1) * TD_N + j];
      float w2 = W4[(k4 * 4 + 2) * TD_N + j];
      float w3v = W4[(k4 * 4 + 3) * TD_N + j];
#pragma unroll
      for (int r = 0; r < 4; r++) {
        float4 sv = S4[r * 64 + k4];
        z2a[r] += sv.x * w0 + sv.y * w1 + sv.z * w2 + sv.w * w3v;
      }
    }
  }
  for (int r = 0; r < 4; r++) z2a[r] += b4[j];
  __syncthreads();
  for (int r = 0; r < 4; r++) {
    float v = z2a[r], v2 = z2a[r] * z2a[r];
    for (int off = 32; off; off >>= 1) { v += __shfl_down(v, off); v2 += __shfl_down(v2, off); }
    if (lane == 0) { red[r][w][0] = v; red[r][w][1] = v2; }
  }
  __syncthreads();
  for (int r = 0; r < 4; r++) {
    float sm = red[r][0][0] + red[r][1][0] + red[r][2][0] + red[r][3][0];
    float sq = red[r][0][1] + red[r][1][1] + red[r][2][1] + red[r][3][1];
    float mean = sm * (1.0f / TD_N);
    float var = sq * (1.0f / TD_N) - mean * mean;
    float rs = 1.0f / sqrtf(var + 1e-5f);
    float val = (z2a[r] - mean) * rs * g4[j] + bt4[j];
    out[(size_t)(r0 + r) * TD_N + j] = tanhf(val);
  }
}

extern "C" void kernel_launch(void* const* d_in, const int* in_sizes, int n_in,
                              void* d_out, int out_size, void* d_ws, size_t ws_size,
                              hipStream_t stream) {
  const float* obs = (const float*)d_in[0];
  const unsigned char* C = (const unsigned char*)d_in[1];
  const float* W1 = (const float*)d_in[2];  const float* b1 = (const float*)d_in[3];
  const float* g1 = (const float*)d_in[4];  const float* bt1 = (const float*)d_in[5];
  const float* W2 = (const float*)d_in[6];  const float* b2 = (const float*)d_in[7];
  const float* g2 = (const float*)d_in[8];  const float* bt2 = (const float*)d_in[9];
  const float* aW1 = (const float*)d_in[10]; const float* ab1 = (const float*)d_in[11];
  const float* aW2 = (const float*)d_in[12]; const float* ab2 = (const float*)d_in[13];
  const float* aW3 = (const float*)d_in[14]; const float* ab3 = (const float*)d_in[15];
  const float* Wih_f = (const float*)d_in[16]; const float* Whh_f = (const float*)d_in[17];
  const float* bih_f = (const float*)d_in[18]; const float* bhh_f = (const float*)d_in[19];
  const float* Wih_r = (const float*)d_in[20]; const float* Whh_r = (const float*)d_in[21];
  const float* bih_r = (const float*)d_in[22]; const float* bhh_r = (const float*)d_in[23];
  const float* W3 = (const float*)d_in[24]; const float* b3 = (const float*)d_in[25];
  const float* g3 = (const float*)d_in[26]; const float* bt3 = (const float*)d_in[27];
  const float* W4 = (const float*)d_in[28]; const float* b4 = (const float*)d_in[29];
  const float* g4 = (const float*)d_in[30]; const float* bt4 = (const float*)d_in[31];
  float* out = (float*)d_out;

  // Workspace layout (float offsets). t_buf overlaps thB (dead before k_scan).
  float* ws = (float*)d_ws;
  unsigned int* wfragf = (unsigned int*)ws;             // 65536 u32
  unsigned int* wfragr = (unsigned int*)(ws + 131072);  // 65536 u32
  unsigned int* whhpf = (unsigned int*)(ws + 262144);   // 32768 u32
  unsigned int* whhpr = (unsigned int*)(ws + 327680);   // 32768 u32
  float* bsumf = ws + 393216;         // 512
  float* bsumr = ws + 393728;         // 512
  float* thB   = ws + 394240;         // 262144 (parity-1 thoughts buffer)
  float* t_buf = ws + 394240;         // overlap: used only before k_prep/k_scan
  int* ibase   = (int*)(ws + 656384);
  int* membi   = ibase;               // 16384
  int* reqi    = ibase + 16384;       // 16384
  int* isin    = ibase + 32768;       // 1024
  int* flag    = ibase + 33792;       // 64
  int* fin     = ibase + 33856;       // 1024
  int* lstart  = ibase + 34880;       // 64 (nact)
  int* llist   = ibase + 34944;       // 1024
  int* verF    = ibase + 35968;       // 1024
  int* verB    = ibase + 36992;       // 1024
  size_t need = (size_t)(656384 + 38016 + 64) * 4;  // ~2.78 MB
  if (ws_size < need) return;  // diagnosable absmax-fail instead of a fault

  (void)in_sizes; (void)n_in; (void)out_size;

  float* thA = out;  // parity-0 thoughts buffer aliases d_out

  k_cdet<<<1, 64, 0, stream>>>(C, flag);
  k_actor1a<<<256, 256, 0, stream>>>(obs, W1, b1, g1, bt1, t_buf);
  k_actor1b<<<256, 256, 0, stream>>>(t_buf, W2, b2, g2, bt2, thA);
  k_att<<<256, 256, 0, stream>>>(thA, aW1, ab1, aW2, ab2, aW3, ab3, isin);
  k_memb<<<1024, 64, 0, stream>>>(C, flag, membi);
  k_req<<<1024, 256, 0, stream>>>(C, flag, membi, isin, reqi);
  k_prep<<<512, 256, 0, stream>>>(Wih_f, Wih_r, Whh_f, Whh_r, bih_f, bhh_f, bih_r, bhh_r,
                                  wfragf, wfragr, whhpf, whhpr, bsumf, bsumr, verF, verB);
  k_lvl<<<1, 64, 0, stream>>>(isin, membi, fin, lstart, llist);
  k_scan<<<NWGC, 512, 0, stream>>>(thA, thB, lstart, llist, membi, reqi, verF, verB,
                                   wfragf, wfragr, whhpf, whhpr, bsumf, bsumr);
  k_actor2<<<256, 256, 0, stream>>>(thA, thB, fin, W3, b3, g3, bt3, W4, b4, g4, bt4, out);
}